// Round 10
// baseline (268.582 us; speedup 1.0000x reference)
//
#include <hip/hip_runtime.h>

// out0 = cumsum(z, axis=0), z fp32 [8192, 64, 128] -> 8192 rows x 8192 contiguous cols.
// out1 = previous_loss (1 float) at d_out[8192*8192].
//
// Two-kernel streaming scan (rounds 5-9: MALL-reuse schemes run at 1.2-2 TB/s
// effective, streaming runs at ~6.9 TB/s, so the 808 MB two-read structure
// wins). This round folds the chunk-prefix scan into k_partial's tail:
// per column-tile arrival counter; the LAST chunk-block of each tile runs that
// tile's 128-deep exclusive scan in place (~1-2 us, overlapped with other
// tiles' partial blocks). Deletes the standalone latency-bound k_scan kernel
// and one launch gap (~8-10 us off the critical path).
// Summation grouping identical to round 3 (absmax 1.0).

typedef float f4 __attribute__((ext_vector_type(4)));

constexpr int NROWS = 8192;
constexpr int NCOLS = 8192;
constexpr int NCOL4 = NCOLS / 4;     // 2048 float4 per row
constexpr int TPB   = 256;
constexpr int KCH   = 128;           // row chunks (chain depth)
constexpr int RR    = NROWS / KCH;   // 64 rows per chunk
constexpr int CT    = NCOL4 / TPB;   // 8 column tiles -> 1024 blocks

// Pass 1: per-column chunk sums -> agg[KCH][NCOL4]; the last-arriving block of
// each tile converts that tile's aggregates to EXCLUSIVE prefixes in place.
__global__ __launch_bounds__(TPB) void k_partial_scan(
    const f4* __restrict__ z, f4* __restrict__ agg,
    unsigned int* __restrict__ cnt,
    const float* __restrict__ prev, float* __restrict__ out_tail)
{
    const int tile  = blockIdx.x & (CT - 1);
    const int chunk = blockIdx.x >> 3;
    const int tid   = threadIdx.x;
    const int c4    = tile * TPB + tid;

    if (blockIdx.x == 0 && tid == 0) out_tail[0] = prev[0];

    // chunk aggregate (nt loads: z is re-read by k_apply from HBM anyway;
    // don't churn the MALL)
    const f4* p = z + (size_t)chunk * RR * NCOL4 + c4;
    f4 a = (f4)0.f;
    #pragma unroll 16
    for (int r = 0; r < RR; ++r)
        a += __builtin_nontemporal_load(&p[(size_t)r * NCOL4]);
    agg[(size_t)chunk * NCOL4 + c4] = a;

    // arrival: last block of this tile scans the tile's 128 chunk aggs.
    __shared__ int lastFlag;
    __syncthreads();                       // all agg writes of this block done
    if (tid == 0) {
        __threadfence();                   // release agg to agent scope
        unsigned int old = __hip_atomic_fetch_add(&cnt[tile], 1u,
                                                  __ATOMIC_ACQ_REL,
                                                  __HIP_MEMORY_SCOPE_AGENT);
        lastFlag = (old == KCH - 1);
    }
    __syncthreads();
    if (!lastFlag) return;

    __builtin_amdgcn_fence(__ATOMIC_ACQUIRE, "agent");
    // in-place exclusive scan: thread tid owns f4-column c4 (unit-stride/wave)
    f4 run = (f4)0.f;
    f4* ap = agg + c4;
    #pragma unroll 16
    for (int k = 0; k < KCH; ++k) {
        f4 t = ap[(size_t)k * NCOL4];
        ap[(size_t)k * NCOL4] = run;
        run += t;
    }
}

// Pass 2: prefix = one load of the exclusive chunk prefix, then stream
// z -> out (nt loads, nt stores), reversed chunk dispatch.
__global__ __launch_bounds__(TPB) void k_apply(const f4* __restrict__ z,
                                               const f4* __restrict__ agg,
                                               f4* __restrict__ out) {
    const int tile  = blockIdx.x & (CT - 1);
    const int chunk = KCH - 1 - (blockIdx.x >> 3);
    const int c4    = tile * TPB + threadIdx.x;

    f4 s = agg[(size_t)chunk * NCOL4 + c4];
    const f4* p = z   + (size_t)chunk * RR * NCOL4 + c4;
    f4*       q = out + (size_t)chunk * RR * NCOL4 + c4;
    #pragma unroll 8
    for (int r = 0; r < RR; ++r) {
        s += __builtin_nontemporal_load(&p[(size_t)r * NCOL4]);
        __builtin_nontemporal_store(s, &q[(size_t)r * NCOL4]);
    }
}

extern "C" void kernel_launch(void* const* d_in, const int* in_sizes, int n_in,
                              void* d_out, int out_size, void* d_ws, size_t ws_size,
                              hipStream_t stream) {
    const f4*    z    = (const f4*)d_in[0];
    const float* prev = (const float*)d_in[1];
    float*       out  = (float*)d_out;
    float*       tail = out + (size_t)NROWS * NCOLS;

    f4*           agg = (f4*)d_ws;                       // 4 MiB
    unsigned int* cnt = (unsigned int*)((char*)d_ws +
                        (size_t)KCH * NCOL4 * sizeof(f4));

    hipMemsetAsync(cnt, 0, CT * sizeof(unsigned int), stream);
    k_partial_scan<<<KCH * CT, TPB, 0, stream>>>(z, agg, cnt, prev, tail);
    k_apply<<<KCH * CT, TPB, 0, stream>>>(z, (const f4*)agg, (f4*)out);
}

// Round 11
// 219.826 us; speedup vs baseline: 1.2218x; 1.2218x over previous
//
#include <hip/hip_runtime.h>

// out0 = cumsum(z, axis=0), z fp32 [8192, 64, 128] -> 8192 rows x 8192 contiguous cols.
// out1 = previous_loss (1 float) at d_out[8192*8192].
//
// Two-kernel streaming scan with the chunk-prefix scan folded into pass 1 via
// a last-block-per-tile arrival counter (r10 structure). r10's regression was
// __builtin_nontemporal_load: nt READS run at ~0.9 TB/s on gfx950 (7x slower
// than normal streaming reads). This round: normal loads everywhere, nt only
// on output STORES (proven fine in r3). Summation grouping identical to
// round 3 (absmax 1.0).

typedef float f4 __attribute__((ext_vector_type(4)));

constexpr int NROWS = 8192;
constexpr int NCOLS = 8192;
constexpr int NCOL4 = NCOLS / 4;     // 2048 float4 per row
constexpr int TPB   = 256;
constexpr int KCH   = 128;           // row chunks (chain depth)
constexpr int RR    = NROWS / KCH;   // 64 rows per chunk
constexpr int CT    = NCOL4 / TPB;   // 8 column tiles -> 1024 blocks

// Pass 1: per-column chunk sums -> agg[KCH][NCOL4]; the last-arriving block of
// each tile converts that tile's aggregates to EXCLUSIVE prefixes in place.
__global__ __launch_bounds__(TPB) void k_partial_scan(
    const f4* __restrict__ z, f4* __restrict__ agg,
    unsigned int* __restrict__ cnt,
    const float* __restrict__ prev, float* __restrict__ out_tail)
{
    const int tile  = blockIdx.x & (CT - 1);
    const int chunk = blockIdx.x >> 3;
    const int tid   = threadIdx.x;
    const int c4    = tile * TPB + tid;

    if (blockIdx.x == 0 && tid == 0) out_tail[0] = prev[0];

    // chunk aggregate (NORMAL loads -- nt loads measured 7x slower, r10)
    const f4* p = z + (size_t)chunk * RR * NCOL4 + c4;
    f4 a = (f4)0.f;
    #pragma unroll 16
    for (int r = 0; r < RR; ++r) a += p[(size_t)r * NCOL4];
    agg[(size_t)chunk * NCOL4 + c4] = a;

    // arrival: last block of this tile scans the tile's 128 chunk aggs.
    __shared__ int lastFlag;
    __syncthreads();                       // all agg writes of this block done
    if (tid == 0) {
        __threadfence();                   // release agg to agent scope
        unsigned int old = __hip_atomic_fetch_add(&cnt[tile], 1u,
                                                  __ATOMIC_ACQ_REL,
                                                  __HIP_MEMORY_SCOPE_AGENT);
        lastFlag = (old == KCH - 1);
    }
    __syncthreads();
    if (!lastFlag) return;

    __builtin_amdgcn_fence(__ATOMIC_ACQUIRE, "agent");
    // in-place exclusive scan: thread tid owns f4-column c4 (coalesced/wave)
    f4 run = (f4)0.f;
    f4* ap = agg + c4;
    #pragma unroll 16
    for (int k = 0; k < KCH; ++k) {
        f4 t = ap[(size_t)k * NCOL4];
        ap[(size_t)k * NCOL4] = run;
        run += t;
    }
}

// Pass 2: prefix = one load of the exclusive chunk prefix, then stream
// z -> out (normal loads, nt stores), reversed chunk dispatch.
__global__ __launch_bounds__(TPB) void k_apply(const f4* __restrict__ z,
                                               const f4* __restrict__ agg,
                                               f4* __restrict__ out) {
    const int tile  = blockIdx.x & (CT - 1);
    const int chunk = KCH - 1 - (blockIdx.x >> 3);
    const int c4    = tile * TPB + threadIdx.x;

    f4 s = agg[(size_t)chunk * NCOL4 + c4];
    const f4* p = z   + (size_t)chunk * RR * NCOL4 + c4;
    f4*       q = out + (size_t)chunk * RR * NCOL4 + c4;
    #pragma unroll 8
    for (int r = 0; r < RR; ++r) {
        s += p[(size_t)r * NCOL4];
        __builtin_nontemporal_store(s, &q[(size_t)r * NCOL4]);
    }
}

extern "C" void kernel_launch(void* const* d_in, const int* in_sizes, int n_in,
                              void* d_out, int out_size, void* d_ws, size_t ws_size,
                              hipStream_t stream) {
    const f4*    z    = (const f4*)d_in[0];
    const float* prev = (const float*)d_in[1];
    float*       out  = (float*)d_out;
    float*       tail = out + (size_t)NROWS * NCOLS;

    f4*           agg = (f4*)d_ws;                       // 4 MiB
    unsigned int* cnt = (unsigned int*)((char*)d_ws +
                        (size_t)KCH * NCOL4 * sizeof(f4));

    hipMemsetAsync(cnt, 0, CT * sizeof(unsigned int), stream);
    k_partial_scan<<<KCH * CT, TPB, 0, stream>>>(z, agg, cnt, prev, tail);
    k_apply<<<KCH * CT, TPB, 0, stream>>>(z, (const f4*)agg, (f4*)out);
}

// Round 12
// 136.600 us; speedup vs baseline: 1.9662x; 1.6093x over previous
//
#include <hip/hip_runtime.h>

// out0 = cumsum(z, axis=0), z fp32 [8192, 64, 128] -> 8192 rows x 8192 contiguous cols.
// out1 = previous_loss (1 float) at d_out[8192*8192].
//
// FINAL: exact round-3 structure -- the measured optimum (136.5 us, within ~2%
// of the composed ceiling ~134 us for the 2-read structure: 268 MB read +
// 268 MB read + 268 MB write + 4 MB scan @ ~6.9/6.5 TB/s + 2 launch gaps).
// Falsified alternatives (rounds 2,4-11): decoupled lookback (cross-XCD flag
// latency), cooperative fused (graph-capture ban + VGPR capacity: chip has
// 128 MiB of VGPR vs 256 MiB of z), MALL-reuse schemes (Infinity-Cache-hit
// read streams deliver only 1-2 TB/s vs 6.9 TB/s HBM streaming), write-
// retention (no retention vs write stream), arrival-counter scan fold
// (per-block agent-scope release fences poison streaming), nt loads (7x read
// slowdown). nt STORES on the output are a measured win (r1->r3).

typedef float f4 __attribute__((ext_vector_type(4)));

constexpr int NROWS = 8192;
constexpr int NCOLS = 8192;
constexpr int NCOL4 = NCOLS / 4;     // 2048 float4 per row
constexpr int TPB   = 256;
constexpr int KCH   = 128;           // row chunks
constexpr int RR    = NROWS / KCH;   // 64 rows per chunk
constexpr int CT    = NCOL4 / TPB;   // 8 column tiles

// Pass 1: per-column sums of each row-chunk -> part[KCH][NCOLS]
__global__ __launch_bounds__(TPB) void k_partial(const f4* __restrict__ z,
                                                 f4* __restrict__ part) {
    const int tile  = blockIdx.x & (CT - 1);
    const int chunk = blockIdx.x >> 3;
    const int c4    = tile * TPB + threadIdx.x;
    const f4* p = z + (size_t)chunk * RR * NCOL4 + c4;
    f4 a = (f4)0.f;
    #pragma unroll 8
    for (int r = 0; r < RR; ++r) a += p[(size_t)r * NCOL4];
    part[(size_t)chunk * NCOL4 + c4] = a;
}

// Pass 2: in-place serial EXCLUSIVE scan over the KCH chunk sums, per column.
// unroll 16 -> independent load groups pipeline the dependent chain.
__global__ __launch_bounds__(TPB) void k_scan(float* __restrict__ part,
                                              const float* __restrict__ prev,
                                              float* __restrict__ out_tail) {
    const int c = blockIdx.x * TPB + threadIdx.x; // 0..8191
    float run = 0.f;
    #pragma unroll 16
    for (int k = 0; k < KCH; ++k) {
        const size_t i = (size_t)k * NCOLS + c;
        float v = part[i];
        part[i] = run;
        run += v;
    }
    if (blockIdx.x == 0 && threadIdx.x == 0) out_tail[0] = prev[0];
}

// Pass 3: re-read z (reverse chunk order), add exclusive chunk prefix, write
// inclusive cumsum with nontemporal stores.
__global__ __launch_bounds__(TPB) void k_apply(const f4* __restrict__ z,
                                               const f4* __restrict__ part,
                                               f4* __restrict__ out) {
    const int tile  = blockIdx.x & (CT - 1);
    const int chunk = KCH - 1 - (blockIdx.x >> 3);   // reversed
    const int c4    = tile * TPB + threadIdx.x;
    f4 a = part[(size_t)chunk * NCOL4 + c4];
    const f4* p = z   + (size_t)chunk * RR * NCOL4 + c4;
    f4*       q = out + (size_t)chunk * RR * NCOL4 + c4;
    #pragma unroll 4
    for (int r = 0; r < RR; ++r) {
        a += p[(size_t)r * NCOL4];
        __builtin_nontemporal_store(a, &q[(size_t)r * NCOL4]);
    }
}

extern "C" void kernel_launch(void* const* d_in, const int* in_sizes, int n_in,
                              void* d_out, int out_size, void* d_ws, size_t ws_size,
                              hipStream_t stream) {
    const f4*    z    = (const f4*)d_in[0];
    const float* prev = (const float*)d_in[1];
    float*       out  = (float*)d_out;
    float*       part = (float*)d_ws;   // KCH*NCOLS floats = 4 MiB
    float*       tail = out + (size_t)NROWS * NCOLS;

    k_partial<<<KCH * CT, TPB, 0, stream>>>(z, (f4*)part);
    k_scan<<<NCOLS / TPB, TPB, 0, stream>>>(part, prev, tail);
    k_apply<<<KCH * CT, TPB, 0, stream>>>(z, (const f4*)part, (f4*)out);
}